// Round 8
// baseline (131.952 us; speedup 1.0000x reference)
//
#include <hip/hip_runtime.h>
#include <math.h>

#define N_ENTC 30000
#define ALL_RELC 221
#define NDIM 32
#define EVAL_RELC 86
#define BB 16
#define NE 120000
#define ROW 512            /* BB*NDIM floats per entity row */
#define NSCAN 120          /* scan blocks; NSCAN*EPB == NE */
#define EPB 1000
#define MW 938             /* bitmask words for 30000 entities */

// Pipeline (stream order = cross-stage sync; one ticket for the epilogue):
//  K1 k_scan : 120 blocks. Packed int4 records per stripe (R7-proven),
//              counts, idempotent zero of hidB rows for L2-record heads,
//              block0: relw -> global, block1: zero qacc + ticket.
//  K2 k_msg1 : 120 blocks. Layer-1 messages (sources = ent_emb via srcmask)
//              atomically accumulated into hidB.
//  K3 k_tail2: 120 blocks. Per L2 record: relu(hidB[h]@W0+b0) into a per-wave
//              LDS tile (pure function -> duplicates benign), immediately
//              scattered as layer-2 messages into qacc. Then each block
//              releases + takes a ticket; the last block acquires and runs
//              the fin epilogue (layer-2 linear + gather + 16x128@128x86).

__global__ __launch_bounds__(512) void k_scan(
    const int* __restrict__ head, const int* __restrict__ tail,
    const int* __restrict__ eh, const int* __restrict__ et,
    const int* __restrict__ er, const float* __restrict__ ew,
    const float* __restrict__ ent_emb,
    const float* __restrict__ Wrel, const float* __restrict__ brel,
    const float* __restrict__ Watt, const float* __restrict__ batt,
    int4* __restrict__ recs, int* __restrict__ counts,
    float* __restrict__ relwG, float* __restrict__ hidB,
    float* __restrict__ qaccB, unsigned* __restrict__ ticket)
{
    __shared__ unsigned mH[MW], mT[MW];
    __shared__ int s_src[32];
    __shared__ int s_cnt[4];
    __shared__ float s_ht[BB * 64];
    __shared__ float s_h5[BB * 5];
    const int t = threadIdx.x, bid = blockIdx.x;

    if (t < 32) s_src[t] = (t < BB) ? head[t] : tail[t - BB];
    for (int i = t; i < MW; i += 512) { mH[i] = 0u; mT[i] = 0u; }
    if (t < 4) s_cnt[t] = 0;
    __syncthreads();
    if (t < BB) {
        int h = s_src[t], q = s_src[BB + t];
        atomicOr(&mH[h >> 5], 1u << (h & 31));
        atomicOr(&mT[q >> 5], 1u << (q & 31));
    }
    __syncthreads();

    const int e0 = bid * EPB;
    const int4* eh4 = (const int4*)(eh + e0);
    const int4* et4 = (const int4*)(et + e0);
    for (int p = t; p < EPB / 4; p += 512) {
        int4 h4 = eh4[p], t4 = et4[p];
        int hv[4] = {h4.x, h4.y, h4.z, h4.w};
        int tv[4] = {t4.x, t4.y, t4.z, t4.w};
#pragma unroll
        for (int c = 0; c < 4; c++) {
            int e = e0 + 4 * p + c, h = hv[c], tt = tv[c];
            bool hH = (mH[h >> 5] >> (h & 31)) & 1u;
            bool hT = (mT[h >> 5] >> (h & 31)) & 1u;
            bool tT = (mT[tt >> 5] >> (tt & 31)) & 1u;
            bool tH = (mH[tt >> 5] >> (tt & 31)) & 1u;
            if (!(hH | hT | tT | tH)) continue;
            int r = er[e];
            int wb = __float_as_int(ew[e]);
            if (hH) { // d=0 layer-1: srcmask over head ids
                unsigned m = 0;
#pragma unroll
                for (int b = 0; b < BB; b++) m |= (s_src[b] == h) ? (1u << b) : 0u;
                int pos = atomicAdd(&s_cnt[0], 1);
                recs[(size_t)bid * EPB + pos] = make_int4(tt, r | (int)(m << 8), wb, h);
            }
            if (hT) { // d=1 layer-1: srcmask over tail ids
                unsigned m = 0;
#pragma unroll
                for (int b = 0; b < BB; b++) m |= (s_src[BB + b] == h) ? (1u << b) : 0u;
                int pos = atomicAdd(&s_cnt[1], 1);
                recs[(size_t)NE + bid * EPB + pos] = make_int4(tt, r | (int)(m << 8), wb, h);
            }
            if (tT) { // d=0 layer-2: canon = first matching tail slot
                unsigned m = 0;
#pragma unroll
                for (int b = 0; b < BB; b++) m |= (s_src[BB + b] == tt) ? (1u << b) : 0u;
                int canon = __ffs(m) - 1;
                int pos = atomicAdd(&s_cnt[2], 1);
                recs[(size_t)2 * NE + bid * EPB + pos] = make_int4(h, r | (canon << 8), wb, tt);
            }
            if (tH) { // d=1 layer-2: canon = first matching head slot
                unsigned m = 0;
#pragma unroll
                for (int b = 0; b < BB; b++) m |= (s_src[b] == tt) ? (1u << b) : 0u;
                int canon = __ffs(m) - 1;
                int pos = atomicAdd(&s_cnt[3], 1);
                recs[(size_t)3 * NE + bid * EPB + pos] = make_int4(h, r | (canon << 8), wb, tt);
            }
        }
    }
    __syncthreads();
    if (t < 4) counts[bid * 4 + t] = s_cnt[t];

    // Idempotent zero of hidB rows for this stripe's L2-record heads.
    {
        const int wid8 = t >> 6, lane = t & 63;
        float4 z = make_float4(0.f, 0.f, 0.f, 0.f);
        for (int li = 2; li < 4; li++) {
            int c = s_cnt[li];
            float* hb = hidB + (size_t)(li - 2) * N_ENTC * ROW;
            for (int j = wid8; j < c; j += 8) {
                int row = recs[(size_t)li * NE + bid * EPB + j].x;
                float4* p = (float4*)(hb + (size_t)row * ROW);
                p[lane] = z;
                p[lane + 64] = z;
            }
        }
    }

    if (bid == 1) { // zero qacc (both directions) + ticket
        for (int i = t; i < 2 * BB * ROW; i += 512) qaccB[i] = 0.f;
        if (t == 0) *ticket = 0u;
    }
    if (bid == 0) { // relation-attention weights -> global (R7-proven math)
        for (int i = t; i < BB * NDIM; i += 512) {
            int b = i >> 5, k = i & 31;
            s_ht[b * 64 + k] = ent_emb[(size_t)s_src[b] * NDIM + k];
            s_ht[b * 64 + 32 + k] = ent_emb[(size_t)s_src[BB + b] * NDIM + k];
        }
        __syncthreads();
        for (int l = 0; l < 2; l++) {
            for (int i = t; i < BB * 5; i += 512) {
                int b = i / 5, j = i % 5;
                float s = brel[l * 5 + j];
                for (int k = 0; k < 64; k++)
                    s += s_ht[b * 64 + k] * Wrel[l * 320 + k * 5 + j];
                s_h5[i] = fmaxf(s, 0.f);
            }
            __syncthreads();
            for (int i = t; i < BB * ALL_RELC; i += 512) {
                int b = i / ALL_RELC, r = i % ALL_RELC;
                float s = batt[l * ALL_RELC + r];
                for (int j = 0; j < 5; j++)
                    s += s_h5[b * 5 + j] * Watt[l * 5 * ALL_RELC + j * ALL_RELC + r];
                relwG[l * BB * ALL_RELC + i] = 1.0f / (1.0f + expf(-s));
            }
            __syncthreads();
        }
    }
}

__global__ __launch_bounds__(256) void k_msg1(
    const int* __restrict__ head, const int* __restrict__ tail,
    const float* __restrict__ ent_emb, const float* __restrict__ rel_embs,
    const int4* __restrict__ recs, const int* __restrict__ counts,
    const float* __restrict__ relwG, float* __restrict__ hidB)
{
    __shared__ int s_src[32];
    const int t = threadIdx.x, bid = blockIdx.x;
    int4 c4 = ((const int4*)counts)[bid];
    if ((c4.x | c4.y) == 0) return;
    if (t < 32) s_src[t] = (t < BB) ? head[t] : tail[t - BB];
    __syncthreads();
    const int wid = t >> 6, lane = t & 63;
    const float4* rv0 = (const float4*)rel_embs;
    for (int d = 0; d < 2; d++) {
        int c = d ? c4.y : c4.x;
        const int4* R = recs + (size_t)d * NE + (size_t)bid * EPB;
        float* hb = hidB + (size_t)d * N_ENTC * ROW;
        for (int j = wid; j < c; j += 4) {
            int4 rec = R[j];
            int tt = rec.x, r = rec.y & 255;
            unsigned msk = ((unsigned)rec.y) >> 8;
            float w = __int_as_float(rec.z);
            float* drow = hb + (size_t)tt * ROW;
#pragma unroll
            for (int ii = 0; ii < 2; ii++) {
                int i4 = lane + 64 * ii, b = i4 >> 3, kq = i4 & 7;
                if (!((msk >> b) & 1u)) continue;
                float cf = relwG[b * ALL_RELC + r] * w;
                float4 sv = ((const float4*)(ent_emb + (size_t)s_src[d * BB + b] * NDIM))[kq];
                float4 rr = rv0[r * 8 + kq];
                atomicAdd(drow + i4 * 4 + 0, sv.x * cf * rr.x);
                atomicAdd(drow + i4 * 4 + 1, sv.y * cf * rr.y);
                atomicAdd(drow + i4 * 4 + 2, sv.z * cf * rr.z);
                atomicAdd(drow + i4 * 4 + 3, sv.w * cf * rr.w);
            }
        }
    }
}

__global__ __launch_bounds__(256) void k_tail2(
    const int* __restrict__ head, const int* __restrict__ tail,
    const float* __restrict__ ent_emb, const float* __restrict__ rel_embs,
    const float* __restrict__ Wlin, const float* __restrict__ blin,
    const float* __restrict__ Wr, const float* __restrict__ br,
    const int4* __restrict__ recs, const int* __restrict__ counts,
    const float* __restrict__ relwG, const float* __restrict__ hidB,
    float* __restrict__ qaccB, unsigned* __restrict__ ticket,
    float* __restrict__ out)
{
    __shared__ float sW[NDIM * NDIM];
    __shared__ float sb[NDIM];
    __shared__ float s_tile[4][512]; // per-wave lin tile; reused as sx in fin
    __shared__ int s_src[32];
    __shared__ int s_canon[2][BB];
    __shared__ unsigned s_last;
    const int t = threadIdx.x, bid = blockIdx.x;
    const int wid = t >> 6, lane = t & 63;

    int4 c4 = ((const int4*)counts)[bid];
    if (c4.z | c4.w) {
        for (int i = t; i < NDIM * NDIM; i += 256) sW[i] = Wlin[i]; // layer 0
        if (t < NDIM) sb[t] = blin[t];
        __syncthreads();
        const int b4 = lane >> 2, j0 = (lane & 3) * 8;
        const float* rw1 = relwG + BB * ALL_RELC;
        const float4* rv1 = (const float4*)(rel_embs + (size_t)ALL_RELC * NDIM);
        float* tw = &s_tile[wid][0];
        for (int d = 0; d < 2; d++) {
            int c = d ? c4.w : c4.z;
            const int4* R = recs + (size_t)(2 + d) * NE + (size_t)bid * EPB;
            const float* hb = hidB + (size_t)d * N_ENTC * ROW;
            float* qa = qaccB + (size_t)d * BB * ROW;
            for (int j = wid; j < c; j += 4) {
                int4 rec = R[j];
                int row = rec.x, r = rec.y & 255, canon = (rec.y >> 8) & 15;
                float w = __int_as_float(rec.z);
                // --- layer-1 linear (pure fn of hidB[row]) -> wave tile ---
                const float4* src = (const float4*)(hb + (size_t)row * ROW + b4 * NDIM);
                float h[NDIM];
#pragma unroll
                for (int q = 0; q < 8; q++) {
                    float4 v = src[q];
                    h[q * 4 + 0] = v.x; h[q * 4 + 1] = v.y;
                    h[q * 4 + 2] = v.z; h[q * 4 + 3] = v.w;
                }
                float acc[8];
#pragma unroll
                for (int jj = 0; jj < 8; jj++) acc[jj] = sb[j0 + jj];
#pragma unroll
                for (int k = 0; k < NDIM; k++) {
                    float4 w0 = *(const float4*)&sW[k * NDIM + j0];
                    float4 w1 = *(const float4*)&sW[k * NDIM + j0 + 4];
                    float hk = h[k];
                    acc[0] += hk * w0.x; acc[1] += hk * w0.y;
                    acc[2] += hk * w0.z; acc[3] += hk * w0.w;
                    acc[4] += hk * w1.x; acc[5] += hk * w1.y;
                    acc[6] += hk * w1.z; acc[7] += hk * w1.w;
                }
                float4 o0, o1;
                o0.x = fmaxf(acc[0], 0.f); o0.y = fmaxf(acc[1], 0.f);
                o0.z = fmaxf(acc[2], 0.f); o0.w = fmaxf(acc[3], 0.f);
                o1.x = fmaxf(acc[4], 0.f); o1.y = fmaxf(acc[5], 0.f);
                o1.z = fmaxf(acc[6], 0.f); o1.w = fmaxf(acc[7], 0.f);
                *(float4*)&tw[b4 * NDIM + j0] = o0;
                *(float4*)&tw[b4 * NDIM + j0 + 4] = o1;
                // --- layer-2 message from tile -> qacc[canon] ---
                // wave-local LDS write->read: same-wave in-order, no barrier
                float* drow = qa + canon * ROW;
#pragma unroll
                for (int ii = 0; ii < 2; ii++) {
                    int i4 = lane + 64 * ii, b = i4 >> 3, kq = i4 & 7;
                    float cf = rw1[b * ALL_RELC + r] * w;
                    float4 s = *(const float4*)&tw[b * NDIM + kq * 4];
                    float4 rr = rv1[r * 8 + kq];
                    atomicAdd(drow + i4 * 4 + 0, s.x * cf * rr.x);
                    atomicAdd(drow + i4 * 4 + 1, s.y * cf * rr.y);
                    atomicAdd(drow + i4 * 4 + 2, s.z * cf * rr.z);
                    atomicAdd(drow + i4 * 4 + 3, s.w * cf * rr.w);
                }
            }
        }
    }
    // ---- ticket: last block runs the fin epilogue ----
    __syncthreads(); // drains all threads' vmcnt (atomics complete)
    if (t == 0) {
        __builtin_amdgcn_fence(__ATOMIC_RELEASE, "agent");
        s_last = __hip_atomic_fetch_add(ticket, 1u, __ATOMIC_RELAXED,
                                        __HIP_MEMORY_SCOPE_AGENT);
    }
    __syncthreads();
    if (s_last != NSCAN - 1) return;
    if (t == 0) __builtin_amdgcn_fence(__ATOMIC_ACQUIRE, "agent");
    __syncthreads();

    // ---- fin epilogue (R7-proven math, 256 threads) ----
    float* sx = &s_tile[0][0]; // [16][128] = hemb|temb|head_hid|tail_hid
    for (int i = t; i < NDIM * NDIM; i += 256) sW[i] = Wlin[NDIM * NDIM + i];
    if (t < NDIM) sb[t] = blin[NDIM + t];
    if (t < 32) s_src[t] = (t < BB) ? head[t] : tail[t - BB];
    __syncthreads();
    if (t < 2 * BB) {
        int d = t >> 4, b = t & 15;
        int q = s_src[(1 - d) * BB + b];
        int c = 0;
        for (int bb = 0; bb < BB; bb++)
            if (s_src[(1 - d) * BB + bb] == q) { c = bb; break; }
        s_canon[d][b] = c;
    }
    for (int i = t; i < BB * NDIM; i += 256) {
        int b = i >> 5, k = i & 31;
        sx[b * 128 + k] = ent_emb[(size_t)s_src[b] * NDIM + k];           // hemb
        sx[b * 128 + 32 + k] = ent_emb[(size_t)s_src[BB + b] * NDIM + k]; // temb
    }
    __syncthreads();
    for (int d = 0; d < 2; d++) { // layer-2 linear on (canon,b) segments
        for (int i = t; i < 512; i += 256) {
            int b = i >> 5, j = i & 31;
            const float* hrow = qaccB + (size_t)d * BB * ROW
                                + s_canon[d][b] * ROW + b * NDIM;
            float s = sb[j];
            for (int k = 0; k < NDIM; k++)
                s += hrow[k] * sW[k * NDIM + j];
            // d=0 (init=head, query=tail) -> tail_hid col 96; d=1 -> head_hid col 64
            sx[b * 128 + (d == 0 ? 96 : 64) + j] = fmaxf(s, 0.f);
        }
    }
    __syncthreads();
    for (int o = t; o < BB * EVAL_RELC; o += 256) {
        int b = o / EVAL_RELC, r = o % EVAL_RELC;
        float s = br[r];
        for (int k = 0; k < 128; k++)
            s += sx[b * 128 + k] * Wr[k * EVAL_RELC + r];
        out[o] = s;
    }
}

extern "C" void kernel_launch(void* const* d_in, const int* in_sizes, int n_in,
                              void* d_out, int out_size, void* d_ws,
                              size_t ws_size, hipStream_t stream)
{
    const int* head = (const int*)d_in[0];
    const int* tail = (const int*)d_in[1];
    const int* eh = (const int*)d_in[2];
    const int* et = (const int*)d_in[3];
    const int* er = (const int*)d_in[4];
    const float* ew = (const float*)d_in[5];
    const float* ent_emb = (const float*)d_in[6];
    const float* rel_embs = (const float*)d_in[7];
    const float* Wlin = (const float*)d_in[8];
    const float* blin = (const float*)d_in[9];
    const float* Wrel = (const float*)d_in[10];
    const float* brel = (const float*)d_in[11];
    const float* Watt = (const float*)d_in[12];
    const float* batt = (const float*)d_in[13];
    const float* Wr = (const float*)d_in[14];
    const float* br = (const float*)d_in[15];
    float* out = (float*)d_out;
    float* ws = (float*)d_ws;

    // ---- workspace carve (~131 MB) ----
    float* hidB = ws;                                        // [2][N][ROW]
    int4* recs = (int4*)(hidB + (size_t)2 * N_ENTC * ROW);   // [4][NE] int4
    int* counts = (int*)(recs + (size_t)4 * NE);             // [NSCAN][4]
    float* relwG = (float*)(counts + 4 * NSCAN);             // 7072
    float* qaccB = relwG + 7072;                             // [2][16][512]
    unsigned* ticket = (unsigned*)(qaccB + 2 * BB * ROW);    // [1]

    k_scan<<<NSCAN, 512, 0, stream>>>(head, tail, eh, et, er, ew, ent_emb,
                                      Wrel, brel, Watt, batt,
                                      recs, counts, relwG, hidB, qaccB, ticket);
    k_msg1<<<NSCAN, 256, 0, stream>>>(head, tail, ent_emb, rel_embs,
                                      recs, counts, relwG, hidB);
    k_tail2<<<NSCAN, 256, 0, stream>>>(head, tail, ent_emb, rel_embs,
                                       Wlin, blin, Wr, br, recs, counts,
                                       relwG, hidB, qaccB, ticket, out);
}